// Round 3
// baseline (73.875 us; speedup 1.0000x reference)
//
#include <hip/hip_runtime.h>

// Problem constants (match reference: B=8192, S=7, C=30)
#define YB     8192
#define YS     7
#define YC     30
#define NCELLS (YB * YS * YS)      // 401408
#define BLOCK  256
#define NBLK   (NCELLS / BLOCK)    // 1568, divides exactly

__device__ __forceinline__ float iou_quirk(float cx1, float cy1, float w1, float h1,
                                           float cx2, float cy2, float w2, float h2) {
    // Faithful replica of reference _iou, including inter/area1 + area2 - inter quirk.
    float area1 = w1 * h1;
    float area2 = w2 * h2;
    float max_left   = fmaxf(cx1 - w1 * 0.5f, cx2 - w2 * 0.5f);
    float min_right  = fminf(cx1 + w1 * 0.5f, cx2 + w2 * 0.5f);
    float max_top    = fmaxf(cy1 - h1 * 0.5f, cy2 - h2 * 0.5f);
    float min_bottom = fminf(cy1 + h1 * 0.5f, cy2 + h2 * 0.5f);
    float inter = (min_right - max_left) * (min_bottom - max_top);
    bool overlap = (max_left < min_right) && (max_top < min_bottom);
    return overlap ? (inter / area1 + area2 - inter) : 0.0f;
}

__global__ __launch_bounds__(BLOCK) void yolo_fused_kernel(const float* __restrict__ preds,
                                                           const float* __restrict__ labels,
                                                           float* __restrict__ partial,
                                                           unsigned int* __restrict__ counter,
                                                           float* __restrict__ out) {
    const int tid = threadIdx.x;
    const long cell = (long)blockIdx.x * BLOCK + tid;   // NCELLS divides exactly

    // Direct per-thread loads: cell base = cell*120 B, always 8B-aligned -> float2.
    // No LDS staging: zero reuse, dense coverage, lines shared via L1.
    const float2* p2 = (const float2*)(preds + cell * YC);
    const float2* l2 = (const float2*)(labels + cell * YC);

    // Box/conf part: elements 0..9 of each.
    float pv[10], lv[10];
    #pragma unroll
    for (int i = 0; i < 5; ++i) {
        float2 a = p2[i]; pv[2 * i] = a.x; pv[2 * i + 1] = a.y;
        float2 b = l2[i]; lv[2 * i] = b.x; lv[2 * i + 1] = b.y;
    }
    // Class part: elements 10..29, accumulate on the fly (keeps VGPRs low).
    float loss_cls = 0.0f;
    #pragma unroll
    for (int i = 5; i < 15; ++i) {
        float2 a = p2[i], b = l2[i];
        float dx = a.x - b.x, dy = a.y - b.y;
        loss_cls += dx * dx + dy * dy;
    }

    float iou1 = iou_quirk(pv[0], pv[1], pv[2], pv[3], lv[0], lv[1], lv[2], lv[3]);
    float iou2 = iou_quirk(pv[5], pv[6], pv[7], pv[8], lv[5], lv[6], lv[7], lv[8]);
    bool resp1 = iou1 > iou2;

    float dx1 = pv[0] - lv[0], dy1 = pv[1] - lv[1];
    float xy1 = dx1 * dx1 + dy1 * dy1;
    float dx2 = pv[5] - lv[5], dy2 = pv[6] - lv[6];
    float xy2 = dx2 * dx2 + dy2 * dy2;

    float sw1 = sqrtf(pv[2]) - sqrtf(lv[2]), sh1 = sqrtf(pv[3]) - sqrtf(lv[3]);
    float wh1 = sw1 * sw1 + sh1 * sh1;
    float sw2 = sqrtf(pv[7]) - sqrtf(lv[7]), sh2 = sqrtf(pv[8]) - sqrtf(lv[8]);
    float wh2 = sw2 * sw2 + sh2 * sh2;

    float d1 = pv[4] - iou1, d2 = pv[9] - iou2;
    float e1 = d1 * d1, e2 = d2 * d2;

    float loss_xy = 5.0f * (resp1 ? xy1 : xy2);
    float loss_wh = resp1 ? wh1 : wh2;
    float loss_obj = resp1 ? e1 : e2;
    float loss_noobj_objcell = 0.5f * (resp1 ? e2 : e1);

    float obj_cell = loss_xy + loss_wh + loss_obj + loss_noobj_objcell + loss_cls;
    float noobj_cell = 0.5f * (pv[4] * pv[4] + pv[9] * pv[9]);

    // labels[...,4] is exactly 0.0 or 1.0
    float v = (lv[4] == 1.0f) ? obj_cell : noobj_cell;

    // Deterministic block reduction: fixed-order wave64 shuffle tree + LDS cross-wave.
    __shared__ float wsum[BLOCK / 64];
    __shared__ int is_last;
    for (int off = 32; off > 0; off >>= 1) v += __shfl_down(v, off);
    const int lane = tid & 63, wid = tid >> 6;
    if (lane == 0) wsum[wid] = v;
    __syncthreads();

    if (tid == 0) {
        partial[blockIdx.x] = wsum[0] + wsum[1] + wsum[2] + wsum[3];
        __threadfence();                                  // device-scope release
        unsigned int prev = atomicAdd(counter, 1u);       // device-scope by default
        is_last = (prev == (unsigned int)(NBLK - 1));
    }
    __syncthreads();

    // Last-arriving block performs the final reduction in FIXED index order
    // (bitwise deterministic regardless of which block runs it).
    if (is_last) {
        __threadfence();                                  // device-scope acquire
        const volatile float* vp = (const volatile float*)partial;
        double s = 0.0;
        for (int i = tid; i < NBLK; i += BLOCK) s += (double)vp[i];
        for (int off = 32; off > 0; off >>= 1) s += __shfl_down(s, off);
        __shared__ double w[BLOCK / 64];
        if (lane == 0) w[wid] = s;
        __syncthreads();
        if (tid == 0) out[0] = (float)((w[0] + w[1] + w[2] + w[3]) / (double)YB);
    }
}

extern "C" void kernel_launch(void* const* d_in, const int* in_sizes, int n_in,
                              void* d_out, int out_size, void* d_ws, size_t ws_size,
                              hipStream_t stream) {
    const float* preds  = (const float*)d_in[0];
    const float* labels = (const float*)d_in[1];
    float* out = (float*)d_out;
    float* partial = (float*)d_ws;                               // NBLK*4 = 6272 B
    unsigned int* counter = (unsigned int*)((char*)d_ws + 6272); // 4 B, total 6276 <= ws

    // Reset the arrival counter every call (graph-capturable memset node).
    hipMemsetAsync(counter, 0, sizeof(unsigned int), stream);
    yolo_fused_kernel<<<NBLK, BLOCK, 0, stream>>>(preds, labels, partial, counter, out);
}